// Round 3
// baseline (482.113 us; speedup 1.0000x reference)
//
#include <hip/hip_runtime.h>
#include <stdint.h>

typedef _Float16 h16;
typedef _Float16 h8v __attribute__((ext_vector_type(8)));
typedef float    f4v __attribute__((ext_vector_type(4)));
typedef int      i4v __attribute__((ext_vector_type(4)));

#define NBATCH 4
#define NNODE  2048
#define DM     256
#define NPAD   2063   // NNODE + 15 (SAME pad: 7 low, 8 high)
#define PARTN  (8192 * 256)

// ---------------- async global->LDS (16B per lane, wave-uniform base + lane*16) ----
__device__ __forceinline__ void async16(const void* g, void* l) {
#if __has_builtin(__builtin_amdgcn_global_load_lds)
  __builtin_amdgcn_global_load_lds((__attribute__((address_space(1))) void*)g,
                                   (__attribute__((address_space(3))) void*)l, 16, 0, 0);
#else
  *(f4v*)l = *(const f4v*)g;
#endif
}

// ---------------- shared 128x128xBK32 MFMA GEMM core, 1-deep pipelined ------------
// A: [128 rows x K], row stride astride (halves). B: [128 cols x K], row stride bstride.
// C[m][n] = sum_k A[m][k] * B[n][k]  (B^T convention).
// Double-buffered LDS (As/Bs each 2x4096 h16). Prefetch for tile k+1 is issued
// AFTER the barrier (so the compiler's auto vmcnt(0)-before-s_barrier coincides
// with our explicit wait at the top of the next iteration -> single barrier/iter,
// load latency hidden behind the MFMA phase).
// XOR swizzle kills the 8-way read bank conflict (slot s of row r holds chunk
// s ^ ((r>>1)&3); reader applies the same XOR).
__device__ __forceinline__ void gemm_tile(
    const h16* Abase, int astride,
    const h16* Bbase, int bstride,
    h16* As, h16* Bs, f4v acc[4][4], int kiters)
{
  const int tid  = threadIdx.x;
  const int lane = tid & 63;
  const int wv   = tid >> 6;
  const int srow = tid >> 2;
  const int sch  = ((tid & 3) ^ ((tid >> 3) & 3)) * 8;   // swizzled source chunk
  const h16* gA0 = Abase + (long)srow * astride + sch;
  const h16* gA1 = Abase + (long)(srow + 64) * astride + sch;
  const h16* gB0 = Bbase + (long)srow * bstride + sch;
  const h16* gB1 = Bbase + (long)(srow + 64) * bstride + sch;
  h16* lA0 = As + tid * 8;
  h16* lA1 = As + 2048 + tid * 8;
  h16* lB0 = Bs + tid * 8;
  h16* lB1 = Bs + 2048 + tid * 8;
  // fragment read offsets: A[m=lane&15][k=quad*8+j], B symmetric, swizzle-corrected
  const int swz = ((lane & 15) >> 1) & 3;
  const int qq  = ((lane >> 4) ^ swz) * 8;
  const int amr = ((wv & 1) * 64 + (lane & 15)) * 32 + qq;
  const int bnr = ((wv >> 1) * 64 + (lane & 15)) * 32 + qq;

  // prologue: tile 0 -> buffer 0
  async16(gA0, lA0); async16(gA1, lA1);
  async16(gB0, lB0); async16(gB1, lB1);

  for (int kt = 0; kt < kiters; ++kt) {
    asm volatile("s_waitcnt vmcnt(0)" ::: "memory");   // tile kt landed
    __syncthreads();                                   // all waves' tile kt landed
    const int cur = (kt & 1) << 12;                    // 4096 halves per buffer
    if (kt + 1 < kiters) {                             // prefetch tile kt+1
      const int nxt = (~kt & 1) << 12;
      const int k0 = (kt + 1) * 32;
      async16(gA0 + k0, lA0 + nxt); async16(gA1 + k0, lA1 + nxt);
      async16(gB0 + k0, lB0 + nxt); async16(gB1 + k0, lB1 + nxt);
    }
    h8v af[4], bf[4];
#pragma unroll
    for (int i = 0; i < 4; ++i) af[i] = *(const h8v*)(As + cur + amr + i * 512);
#pragma unroll
    for (int j = 0; j < 4; ++j) bf[j] = *(const h8v*)(Bs + cur + bnr + j * 512);
#pragma unroll
    for (int i = 0; i < 4; ++i)
#pragma unroll
      for (int j = 0; j < 4; ++j)
        acc[i][j] = __builtin_amdgcn_mfma_f32_16x16x32_f16(af[i], bf[j], acc[i][j], 0, 0, 0);
  }
}

__device__ __forceinline__ void zero_acc(f4v acc[4][4]) {
#pragma unroll
  for (int i = 0; i < 4; ++i)
#pragma unroll
    for (int j = 0; j < 4; ++j) {
      f4v z = {0.f, 0.f, 0.f, 0.f};
      acc[i][j] = z;
    }
}

// ---------------- prep kernels ----------------------------------------------------
__global__ void prep_src_kernel(const float* __restrict__ src, h16* __restrict__ Xpad) {
  int idx = blockIdx.x * 256 + threadIdx.x;          // over NBATCH*NPAD*DM
  int c = idx & 255;
  int row = idx >> 8;
  int b = row / NPAD;
  int n = row - b * NPAD;
  float v = 0.f;
  int ns = n - 7;
  if (ns >= 0 && ns < NNODE) v = src[((long)b * NNODE + ns) * DM + c];
  Xpad[idx] = (h16)v;
}

__global__ void prep_wconv_kernel(const float* __restrict__ Wq, const float* __restrict__ Wk,
                                  const float* __restrict__ Wv, h16* __restrict__ Wt) {
  int idx = blockIdx.x * 256 + threadIdx.x;          // over 3 * 256 * 4096
  int w = idx >> 20;
  int rem = idx & 1048575;
  int o = rem >> 12;
  int tc = rem & 4095;
  int t = tc >> 8;
  int c = tc & 255;
  const float* W = (w == 0) ? Wq : (w == 1) ? Wk : Wv;
  Wt[idx] = (h16)W[(o * 256 + c) * 16 + t];          // [o][c][t] -> [o][t][c]
}

__global__ void prep_wlin_kernel(const float* __restrict__ W1, const float* __restrict__ W2,
                                 const float* __restrict__ W3, h16* __restrict__ Wl) {
  int idx = blockIdx.x * 256 + threadIdx.x;          // over 3 * 65536
  int w = idx >> 16;
  int rem = idx & 65535;
  const float* W = (w == 0) ? W1 : (w == 1) ? W2 : W3;
  Wl[idx] = (h16)W[rem];
}

// ---------------- conv GEMM: Q/K [m][o] f16, V transposed [b][o][n] f16 -----------
__global__ __launch_bounds__(256) void conv_gemm_kernel(
    const h16* __restrict__ Xpad, const h16* __restrict__ Wt,
    const float* __restrict__ bq, const float* __restrict__ bk, const float* __restrict__ bv,
    h16* __restrict__ Q, h16* __restrict__ Ko, h16* __restrict__ Vt)
{
  __shared__ __align__(16) h16 As[8192];
  __shared__ __align__(16) h16 Bs[8192];
  const int mt = blockIdx.x, ct = blockIdx.y, w = blockIdx.z;
  const int m0 = mt * 128;
  const int b = m0 >> 11, n0 = m0 & 2047;
  const h16* Abase = Xpad + ((long)(b * NPAD + n0)) * DM;
  const h16* Bbase = Wt + (long)w * (256 * 4096) + (long)ct * 128 * 4096;
  f4v acc[4][4];
  zero_acc(acc);
  gemm_tile(Abase, DM, Bbase, 4096, As, Bs, acc, 128);

  const float* bias = (w == 0) ? bq : (w == 1) ? bk : bv;
  const int lane = threadIdx.x & 63, wv = threadIdx.x >> 6;
  const int rbase = (wv & 1) * 64 + (lane >> 4) * 4;
  const int cbase = (wv >> 1) * 64 + (lane & 15);
#pragma unroll
  for (int j = 0; j < 4; ++j) {
    const int gc = ct * 128 + cbase + j * 16;
    const float bias_v = bias[gc];
#pragma unroll
    for (int i = 0; i < 4; ++i) {
#pragma unroll
      for (int e = 0; e < 4; ++e) {
        const int gr = m0 + rbase + i * 16 + e;
        const float v = acc[i][j][e] + bias_v;
        if (w == 2) {
          const int bb = gr >> 11, n = gr & 2047;
          Vt[((long)(bb * 256 + gc)) * 2048 + n] = (h16)v;
        } else {
          h16* dst = (w == 0) ? Q : Ko;
          dst[(long)gr * 256 + gc] = (h16)v;
        }
      }
    }
  }
}

// ---------------- scores GEMM: S[b][n][m] f16 = (Q.K^T)*scale ---------------------
__global__ __launch_bounds__(256) void scores_gemm_kernel(
    const h16* __restrict__ Q, const h16* __restrict__ Km, h16* __restrict__ Sh)
{
  __shared__ __align__(16) h16 As[8192];
  __shared__ __align__(16) h16 Bs[8192];
  const int nt = blockIdx.x, mt = blockIdx.y, b = blockIdx.z;
  const h16* Abase = Q + ((long)b * NNODE + nt * 128) * 256;
  const h16* Bbase = Km + ((long)b * NNODE + mt * 128) * 256;
  f4v acc[4][4];
  zero_acc(acc);
  gemm_tile(Abase, 256, Bbase, 256, As, Bs, acc, 8);

  const int lane = threadIdx.x & 63, wv = threadIdx.x >> 6;
  const int rbase = (wv & 1) * 64 + (lane >> 4) * 4;
  const int cbase = (wv >> 1) * 64 + (lane & 15);
  h16* Srow = Sh + (long)b * NNODE * NNODE;
#pragma unroll
  for (int i = 0; i < 4; ++i) {
#pragma unroll
    for (int e = 0; e < 4; ++e) {
      const long row = nt * 128 + rbase + i * 16 + e;
#pragma unroll
      for (int j = 0; j < 4; ++j) {
        const int col = mt * 128 + cbase + j * 16;
        Srow[row * 2048 + col] = (h16)(acc[i][j][e] * 0.0625f);
      }
    }
  }
}

// ---------------- fused mask + softmax + x_lst_new + attn(f16, in-place) ----------
__device__ __forceinline__ float wred_max(float v) {
#pragma unroll
  for (int off = 32; off > 0; off >>= 1) v = fmaxf(v, __shfl_xor(v, off, 64));
  return v;
}
__device__ __forceinline__ float wred_sum(float v) {
#pragma unroll
  for (int off = 32; off > 0; off >>= 1) v += __shfl_xor(v, off, 64);
  return v;
}

__global__ __launch_bounds__(256) void softmax_kernel(
    h16* __restrict__ Sh, const float* __restrict__ dis, const int* __restrict__ adj,
    const float* __restrict__ x_lst, float* __restrict__ out_x)
{
  const int r = blockIdx.x;                 // 0..8191 (b*2048+n)
  const long ro = (long)r * 2048;
  const int tid = threadIdx.x, lane = tid & 63, wv = tid >> 6;
  const int j0 = tid * 8;
  __shared__ float wmax[4], wsum[4];

  h8v sv = *(const h8v*)(Sh + ro + j0);
  f4v d0 = *(const f4v*)(dis + ro + j0);
  f4v d1 = *(const f4v*)(dis + ro + j0 + 4);
  i4v a0 = *(const i4v*)(adj + ro + j0);
  i4v a1 = *(const i4v*)(adj + ro + j0 + 4);

  float s[8];
#pragma unroll
  for (int k = 0; k < 4; ++k) s[k]     = (a0[k] > 0) ? ((float)sv[k]     - d0[k]) : -1e9f;
#pragma unroll
  for (int k = 0; k < 4; ++k) s[k + 4] = (a1[k] > 0) ? ((float)sv[k + 4] - d1[k]) : -1e9f;

  float m = s[0];
#pragma unroll
  for (int k = 1; k < 8; ++k) m = fmaxf(m, s[k]);
  m = wred_max(m);
  if (lane == 0) wmax[wv] = m;
  __syncthreads();
  m = fmaxf(fmaxf(wmax[0], wmax[1]), fmaxf(wmax[2], wmax[3]));

  float p[8], ls = 0.f;
#pragma unroll
  for (int k = 0; k < 8; ++k) { p[k] = __expf(s[k] - m); ls += p[k]; }
  ls = wred_sum(ls);
  if (lane == 0) wsum[wv] = ls;
  __syncthreads();
  const float inv = 1.0f / (wsum[0] + wsum[1] + wsum[2] + wsum[3]);

  // all reads of Sh happened before the first barrier -> in-place write is safe
  f4v x0 = *(const f4v*)(x_lst + ro + j0);
  f4v x1 = *(const f4v*)(x_lst + ro + j0 + 4);
  f4v o0, o1;
  h8v pv;
#pragma unroll
  for (int k = 0; k < 4; ++k) {
    const float a = p[k] * inv, bq = p[k + 4] * inv;
    o0[k] = x0[k] + a; o1[k] = x1[k] + bq;
    pv[k] = (h16)a; pv[k + 4] = (h16)bq;
  }
  *(f4v*)(out_x + ro + j0) = o0;
  *(f4v*)(out_x + ro + j0 + 4) = o1;
  *(h8v*)(Sh + ro + j0) = pv;
}

// ---------------- AV GEMM (split-K x2): X1p[ks][m][d] f32 partials ----------------
__global__ __launch_bounds__(256) void av_gemm_kernel(
    const h16* __restrict__ Attn, const h16* __restrict__ Vt, float* __restrict__ X1p)
{
  __shared__ __align__(16) h16 As[8192];
  __shared__ __align__(16) h16 Bs[8192];
  const int nt = blockIdx.x, b = blockIdx.z;
  const int ct = blockIdx.y & 1, ks = blockIdx.y >> 1;   // y in [0,4): col-tile x k-split
  const h16* Abase = Attn + ((long)b * NNODE + nt * 128) * 2048 + ks * 1024;
  const h16* Bbase = Vt + ((long)b * 256 + ct * 128) * 2048 + ks * 1024;
  f4v acc[4][4];
  zero_acc(acc);
  gemm_tile(Abase, 2048, Bbase, 2048, As, Bs, acc, 32);

  const int lane = threadIdx.x & 63, wv = threadIdx.x >> 6;
  const int rbase = (wv & 1) * 64 + (lane >> 4) * 4;
  const int cbase = (wv >> 1) * 64 + (lane & 15);
  float* dst = X1p + (long)ks * PARTN;
#pragma unroll
  for (int i = 0; i < 4; ++i) {
#pragma unroll
    for (int e = 0; e < 4; ++e) {
      const long row = (long)b * NNODE + nt * 128 + rbase + i * 16 + e;
#pragma unroll
      for (int j = 0; j < 4; ++j) {
        const int col = ct * 128 + cbase + j * 16;
        dst[row * 256 + col] = acc[i][j][e];
      }
    }
  }
}

// ---------------- MLP GEMM: out = act(A.W^T + bias) -------------------------------
__global__ __launch_bounds__(256) void mlp_gemm_kernel(
    const h16* __restrict__ A, const h16* __restrict__ W, const float* __restrict__ bias,
    h16* __restrict__ outH, float* __restrict__ outF)
{
  __shared__ __align__(16) h16 As[8192];
  __shared__ __align__(16) h16 Bs[8192];
  const int mt = blockIdx.x, ct = blockIdx.y;
  const h16* Abase = A + (long)mt * 128 * 256;
  const h16* Bbase = W + (long)ct * 128 * 256;
  f4v acc[4][4];
  zero_acc(acc);
  gemm_tile(Abase, 256, Bbase, 256, As, Bs, acc, 8);

  const int lane = threadIdx.x & 63, wv = threadIdx.x >> 6;
  const int rbase = (wv & 1) * 64 + (lane >> 4) * 4;
  const int cbase = (wv >> 1) * 64 + (lane & 15);
#pragma unroll
  for (int j = 0; j < 4; ++j) {
    const int gc = ct * 128 + cbase + j * 16;
    const float bias_v = bias[gc];
#pragma unroll
    for (int i = 0; i < 4; ++i) {
#pragma unroll
      for (int e = 0; e < 4; ++e) {
        const long gr = (long)mt * 128 + rbase + i * 16 + e;
        float v = acc[i][j][e] + bias_v;
        if (outH) {
          v = (v >= 0.f) ? v : 0.01f * v;   // leaky_relu
          outH[gr * 256 + gc] = (h16)v;
        } else {
          outF[gr * 256 + gc] = v;
        }
      }
    }
  }
}

// ---------------- fused residual(+partial-sum) + LayerNorm ------------------------
__global__ __launch_bounds__(256) void ln_kernel(
    const float* __restrict__ X, const float* __restrict__ Y, const float* __restrict__ Y2,
    const float* __restrict__ g, const float* __restrict__ bb,
    float* __restrict__ outF, h16* __restrict__ outH)
{
  const int wv = threadIdx.x >> 6, lane = threadIdx.x & 63;
  const long r = (long)blockIdx.x * 4 + wv;
  const long off = r * 256 + lane * 4;
  f4v x = *(const f4v*)(X + off);
  f4v y = *(const f4v*)(Y + off);
  if (Y2) {
    f4v y2 = *(const f4v*)(Y2 + off);
#pragma unroll
    for (int k = 0; k < 4; ++k) y[k] += y2[k];
  }
  float v[4];
  float sum = 0.f, sq = 0.f;
#pragma unroll
  for (int k = 0; k < 4; ++k) { v[k] = x[k] + y[k]; sum += v[k]; sq += v[k] * v[k]; }
  sum = wred_sum(sum);
  sq  = wred_sum(sq);
  const float mu = sum * (1.0f / 256.0f);
  const float var = sq * (1.0f / 256.0f) - mu * mu;
  const float rs = rsqrtf(var + 1e-5f);
  f4v gg = *(const f4v*)(g + lane * 4);
  f4v be = *(const f4v*)(bb + lane * 4);
  f4v o;
#pragma unroll
  for (int k = 0; k < 4; ++k) o[k] = (v[k] - mu) * rs * gg[k] + be[k];
  if (outF) *(f4v*)(outF + off) = o;
  if (outH) {
    _Float16 hv[4];
#pragma unroll
    for (int k = 0; k < 4; ++k) hv[k] = (h16)o[k];
    *(ulong1*)(outH + off) = *(ulong1*)hv;
  }
}

// ---------------- launch ----------------------------------------------------------
extern "C" void kernel_launch(void* const* d_in, const int* in_sizes, int n_in,
                              void* d_out, int out_size, void* d_ws, size_t ws_size,
                              hipStream_t stream)
{
  const float* src  = (const float*)d_in[0];
  const float* xlst = (const float*)d_in[1];
  const int*   adj  = (const int*)d_in[2];
  const float* dis  = (const float*)d_in[3];
  const float* Wq   = (const float*)d_in[4];
  const float* bq   = (const float*)d_in[5];
  const float* Wk   = (const float*)d_in[6];
  const float* bk   = (const float*)d_in[7];
  const float* Wv   = (const float*)d_in[8];
  const float* bvp  = (const float*)d_in[9];
  const float* W1   = (const float*)d_in[10];
  const float* b1   = (const float*)d_in[11];
  const float* W2   = (const float*)d_in[12];
  const float* b2   = (const float*)d_in[13];
  const float* W3   = (const float*)d_in[14];
  const float* b3   = (const float*)d_in[15];
  const float* g1   = (const float*)d_in[16];
  const float* be1  = (const float*)d_in[17];
  const float* g2   = (const float*)d_in[18];
  const float* be2  = (const float*)d_in[19];
  (void)in_sizes; (void)n_in; (void)out_size; (void)ws_size;

  char* ws = (char*)d_ws;
  size_t off = 0;
  auto alloc = [&](size_t bytes) -> void* {
    void* p = ws + off;
    off += (bytes + 1023) & ~(size_t)1023;
    return p;
  };
  h16*   Xpad = (h16*)  alloc((size_t)NBATCH * NPAD * DM * 2);       // 4.2 MB
  h16*   Wt   = (h16*)  alloc((size_t)3 * 256 * 4096 * 2);           // 6.3 MB
  h16*   Wl   = (h16*)  alloc((size_t)3 * 256 * 256 * 2);            // 0.4 MB
  h16*   Qb   = (h16*)  alloc((size_t)NBATCH * NNODE * DM * 2);      // 4 MB
  h16*   Kb   = (h16*)  alloc((size_t)NBATCH * NNODE * DM * 2);      // 4 MB
  h16*   Vt   = (h16*)  alloc((size_t)NBATCH * DM * NNODE * 2);      // 4 MB
  h16*   Sh   = (h16*)  alloc((size_t)NBATCH * NNODE * NNODE * 2);   // 32 MB (reused as attn f16)
  float* X1p  = (float*)alloc((size_t)2 * PARTN * 4);                // 16.8 MB (2 split-K partials)
  float* H    = (float*)alloc((size_t)NBATCH * NNODE * DM * 4);      // 8 MB
  h16*   H16  = (h16*)  alloc((size_t)NBATCH * NNODE * DM * 2);      // 4 MB
  h16*   M1   = (h16*)  alloc((size_t)NBATCH * NNODE * DM * 2);      // 4 MB
  h16*   M2   = (h16*)  alloc((size_t)NBATCH * NNODE * DM * 2);      // 4 MB
  float* M3   = X1p;   // partials consumed by ln1 before MLP layer 3 writes

  float* out_h = (float*)d_out;                        // [B,N,d]
  float* out_x = out_h + (size_t)NBATCH * NNODE * DM;  // [B,N,N]

  prep_src_kernel<<<(NBATCH * NPAD * DM) / 256, 256, 0, stream>>>(src, Xpad);
  prep_wconv_kernel<<<(3 * 256 * 4096) / 256, 256, 0, stream>>>(Wq, Wk, Wv, Wt);
  prep_wlin_kernel<<<(3 * 256 * 256) / 256, 256, 0, stream>>>(W1, W2, W3, Wl);

  conv_gemm_kernel<<<dim3(64, 2, 3), 256, 0, stream>>>(Xpad, Wt, bq, bk, bvp, Qb, Kb, Vt);
  scores_gemm_kernel<<<dim3(16, 16, 4), 256, 0, stream>>>(Qb, Kb, Sh);
  softmax_kernel<<<NBATCH * NNODE, 256, 0, stream>>>(Sh, dis, adj, xlst, out_x);
  av_gemm_kernel<<<dim3(16, 4, 4), 256, 0, stream>>>(Sh, Vt, X1p);
  ln_kernel<<<(NBATCH * NNODE) / 4, 256, 0, stream>>>(src, X1p, X1p + PARTN, g1, be1, H, H16);
  mlp_gemm_kernel<<<dim3(64, 2), 256, 0, stream>>>(H16, Wl, b1, M1, nullptr);
  mlp_gemm_kernel<<<dim3(64, 2), 256, 0, stream>>>(M1, Wl + 65536, b2, M2, nullptr);
  mlp_gemm_kernel<<<dim3(64, 2), 256, 0, stream>>>(M2, Wl + 2 * 65536, b3, nullptr, M3);
  ln_kernel<<<(NBATCH * NNODE) / 4, 256, 0, stream>>>(H, M3, nullptr, g2, be2, out_h, nullptr);
}

// Round 4
// 462.770 us; speedup vs baseline: 1.0418x; 1.0418x over previous
//
#include <hip/hip_runtime.h>
#include <stdint.h>

typedef _Float16 h16;
typedef _Float16 h8v __attribute__((ext_vector_type(8)));
typedef float    f4v __attribute__((ext_vector_type(4)));
typedef int      i4v __attribute__((ext_vector_type(4)));

#define NBATCH 4
#define NNODE  2048
#define DM     256
#define NPAD   2063       // NNODE + 15 (SAME pad: 7 low, 8 high)
#define QKELEM 2097152    // 8192*256 elements (one conv output / one split partial)
#define PARTN  (8192 * 256)

// ---------------- async global->LDS (16B per lane, wave-uniform base + lane*16) ----
__device__ __forceinline__ void async16(const void* g, void* l) {
#if __has_builtin(__builtin_amdgcn_global_load_lds)
  __builtin_amdgcn_global_load_lds((__attribute__((address_space(1))) void*)g,
                                   (__attribute__((address_space(3))) void*)l, 16, 0, 0);
#else
  *(f4v*)l = *(const f4v*)g;
#endif
}

// ---------------- shared 128x128xBK32 MFMA GEMM core (round-2 proven version) -----
// Single-buffer, 2-barrier K-loop. Do NOT re-add source-level pipelining: explicit
// dbuf regressed 88.5->107.9 us here (matches learn_hip m99/m131-141). Occupancy
// (blocks/CU) is what hides the latency, supplied by the grid (split-K).
// XOR swizzle kills the 8-way LDS read conflict (verified: 6.29M -> 0).
__device__ __forceinline__ void gemm_tile(
    const h16* Abase, int astride,
    const h16* Bbase, int bstride,
    h16* As, h16* Bs, f4v acc[4][4], int kiters)
{
  const int tid  = threadIdx.x;
  const int lane = tid & 63;
  const int wv   = tid >> 6;
  const int srow = tid >> 2;
  const int sch  = ((tid & 3) ^ ((tid >> 3) & 3)) * 8;   // swizzled source chunk
  const h16* gA0 = Abase + (long)srow * astride + sch;
  const h16* gA1 = Abase + (long)(srow + 64) * astride + sch;
  const h16* gB0 = Bbase + (long)srow * bstride + sch;
  const h16* gB1 = Bbase + (long)(srow + 64) * bstride + sch;
  h16* lA0 = As + tid * 8;
  h16* lA1 = As + 2048 + tid * 8;
  h16* lB0 = Bs + tid * 8;
  h16* lB1 = Bs + 2048 + tid * 8;
  // fragment read offsets: A[m=lane&15][k=quad*8+j], B symmetric, swizzle-corrected
  const int swz = ((lane & 15) >> 1) & 3;
  const int qq  = ((lane >> 4) ^ swz) * 8;
  const int amr = ((wv & 1) * 64 + (lane & 15)) * 32 + qq;
  const int bnr = ((wv >> 1) * 64 + (lane & 15)) * 32 + qq;

  for (int kt = 0; kt < kiters; ++kt) {
    const int k0 = kt * 32;
    __syncthreads();
    async16(gA0 + k0, lA0);
    async16(gA1 + k0, lA1);
    async16(gB0 + k0, lB0);
    async16(gB1 + k0, lB1);
    asm volatile("s_waitcnt vmcnt(0)" ::: "memory");
    __syncthreads();
    h8v af[4], bf[4];
#pragma unroll
    for (int i = 0; i < 4; ++i) af[i] = *(const h8v*)(As + amr + i * 512);
#pragma unroll
    for (int j = 0; j < 4; ++j) bf[j] = *(const h8v*)(Bs + bnr + j * 512);
#pragma unroll
    for (int i = 0; i < 4; ++i)
#pragma unroll
      for (int j = 0; j < 4; ++j)
        acc[i][j] = __builtin_amdgcn_mfma_f32_16x16x32_f16(af[i], bf[j], acc[i][j], 0, 0, 0);
  }
}

__device__ __forceinline__ void zero_acc(f4v acc[4][4]) {
#pragma unroll
  for (int i = 0; i < 4; ++i)
#pragma unroll
    for (int j = 0; j < 4; ++j) {
      f4v z = {0.f, 0.f, 0.f, 0.f};
      acc[i][j] = z;
    }
}

// ---------------- prep kernels ----------------------------------------------------
__global__ void prep_src_kernel(const float* __restrict__ src, h16* __restrict__ Xpad) {
  int idx = blockIdx.x * 256 + threadIdx.x;          // over NBATCH*NPAD*DM
  int c = idx & 255;
  int row = idx >> 8;
  int b = row / NPAD;
  int n = row - b * NPAD;
  float v = 0.f;
  int ns = n - 7;
  if (ns >= 0 && ns < NNODE) v = src[((long)b * NNODE + ns) * DM + c];
  Xpad[idx] = (h16)v;
}

// one block per (w,o): coalesced read of W[o][c][t], LDS transpose, coalesced
// write of Wt[w][o][t][c]. (Old version did 64B-strided scalar reads.)
__global__ __launch_bounds__(256) void prep_wconv_kernel(
    const float* __restrict__ Wq, const float* __restrict__ Wk,
    const float* __restrict__ Wv, h16* __restrict__ Wt)
{
  __shared__ float lds[16][257];
  const int w = blockIdx.x >> 8, o = blockIdx.x & 255, tid = threadIdx.x;
  const float* W = (w == 0) ? Wq : (w == 1) ? Wk : Wv;
  const float* base = W + (long)o * 4096;            // [c][t], row c = 16 floats
  f4v r0 = *(const f4v*)(base + tid * 16);
  f4v r1 = *(const f4v*)(base + tid * 16 + 4);
  f4v r2 = *(const f4v*)(base + tid * 16 + 8);
  f4v r3 = *(const f4v*)(base + tid * 16 + 12);
#pragma unroll
  for (int k = 0; k < 4; ++k) {
    lds[k][tid] = r0[k]; lds[4 + k][tid] = r1[k];
    lds[8 + k][tid] = r2[k]; lds[12 + k][tid] = r3[k];
  }
  __syncthreads();
  const int t = tid >> 4, c0 = (tid & 15) * 16;
  h16* out = Wt + ((long)(w * 256 + o)) * 4096 + t * 256 + c0;
  h8v o0, o1;
#pragma unroll
  for (int k = 0; k < 8; ++k) { o0[k] = (h16)lds[t][c0 + k]; o1[k] = (h16)lds[t][c0 + 8 + k]; }
  *(h8v*)out = o0;
  *(h8v*)(out + 8) = o1;
}

__global__ void prep_wlin_kernel(const float* __restrict__ W1, const float* __restrict__ W2,
                                 const float* __restrict__ W3, h16* __restrict__ Wl) {
  int idx = blockIdx.x * 256 + threadIdx.x;          // over 3 * 65536
  int w = idx >> 16;
  int rem = idx & 65535;
  const float* W = (w == 0) ? W1 : (w == 1) ? W2 : W3;
  Wl[idx] = (h16)W[rem];
}

// ---------------- conv GEMM, split-K x4: f16 partials ------------------------------
// z = w*4 + ks. Q/K partials [ks][m][c]; V partials pre-transposed [ks][b][d][m].
__global__ __launch_bounds__(256) void conv_gemm_kernel(
    const h16* __restrict__ Xpad, const h16* __restrict__ Wt,
    h16* __restrict__ Qp, h16* __restrict__ Kp, h16* __restrict__ Vp)
{
  __shared__ __align__(16) h16 As[4096];
  __shared__ __align__(16) h16 Bs[4096];
  const int mt = blockIdx.x, ct = blockIdx.y;
  const int w = blockIdx.z >> 2, ks = blockIdx.z & 3;
  const int m0 = mt * 128;
  const int b = m0 >> 11, n0 = m0 & 2047;
  const h16* Abase = Xpad + ((long)(b * NPAD + n0)) * DM + ks * 1024;
  const h16* Bbase = Wt + (long)w * (256 * 4096) + (long)ct * 128 * 4096 + ks * 1024;
  f4v acc[4][4];
  zero_acc(acc);
  gemm_tile(Abase, DM, Bbase, 4096, As, Bs, acc, 32);

  h16* dst = ((w == 0) ? Qp : (w == 1) ? Kp : Vp) + (long)ks * QKELEM;
  const int lane = threadIdx.x & 63, wv = threadIdx.x >> 6;
  const int rbase = (wv & 1) * 64 + (lane >> 4) * 4;
  const int cbase = (wv >> 1) * 64 + (lane & 15);
#pragma unroll
  for (int j = 0; j < 4; ++j) {
    const int gc = ct * 128 + cbase + j * 16;
#pragma unroll
    for (int i = 0; i < 4; ++i) {
#pragma unroll
      for (int e = 0; e < 4; ++e) {
        const int gr = m0 + rbase + i * 16 + e;
        const h16 v = (h16)acc[i][j][e];
        if (w == 2) {
          const int bb = gr >> 11, n = gr & 2047;
          dst[((long)(bb * 256 + gc)) * 2048 + n] = v;
        } else {
          dst[(long)gr * 256 + gc] = v;
        }
      }
    }
  }
}

// ---------------- conv reduce: sum 4 partials + bias -> Q,K [m][c], Vt [b][d][m] --
__global__ __launch_bounds__(256) void conv_reduce_kernel(
    const h16* __restrict__ Qp, const h16* __restrict__ Kp, const h16* __restrict__ Vp,
    const float* __restrict__ bq, const float* __restrict__ bk, const float* __restrict__ bv,
    h16* __restrict__ Qb, h16* __restrict__ Kb, h16* __restrict__ Vt)
{
  const long gid = (long)blockIdx.x * 256 + threadIdx.x;
  if (gid < 2 * (QKELEM / 8)) {
    const int which = gid >= (QKELEM / 8);
    const long e = (gid - (long)which * (QKELEM / 8)) * 8;
    const h16* P = which ? Kp : Qp;
    const float* bias = which ? bk : bq;
    float s[8] = {0.f, 0.f, 0.f, 0.f, 0.f, 0.f, 0.f, 0.f};
#pragma unroll
    for (int ks = 0; ks < 4; ++ks) {
      h8v p = *(const h8v*)(P + (long)ks * QKELEM + e);
#pragma unroll
      for (int k = 0; k < 8; ++k) s[k] += (float)p[k];
    }
    const int c0 = (int)(e & 255);
    h8v o;
#pragma unroll
    for (int k = 0; k < 8; ++k) o[k] = (h16)(s[k] + bias[c0 + k]);
    *(h8v*)((which ? Kb : Qb) + e) = o;
  } else {
    const long e = (gid - 2 * (QKELEM / 8)) * 8;     // over [b][d][m]
    float s[8] = {0.f, 0.f, 0.f, 0.f, 0.f, 0.f, 0.f, 0.f};
#pragma unroll
    for (int ks = 0; ks < 4; ++ks) {
      h8v p = *(const h8v*)(Vp + (long)ks * QKELEM + e);
#pragma unroll
      for (int k = 0; k < 8; ++k) s[k] += (float)p[k];
    }
    const float bias_v = bv[(int)((e >> 11) & 255)];
    h8v o;
#pragma unroll
    for (int k = 0; k < 8; ++k) o[k] = (h16)(s[k] + bias_v);
    *(h8v*)(Vt + e) = o;
  }
}

// ---------------- scores GEMM: S[b][n][m] f16 = (Q.K^T)*scale ---------------------
__global__ __launch_bounds__(256) void scores_gemm_kernel(
    const h16* __restrict__ Q, const h16* __restrict__ Km, h16* __restrict__ Sh)
{
  __shared__ __align__(16) h16 As[4096];
  __shared__ __align__(16) h16 Bs[4096];
  const int nt = blockIdx.x, mt = blockIdx.y, b = blockIdx.z;
  const h16* Abase = Q + ((long)b * NNODE + nt * 128) * 256;
  const h16* Bbase = Km + ((long)b * NNODE + mt * 128) * 256;
  f4v acc[4][4];
  zero_acc(acc);
  gemm_tile(Abase, 256, Bbase, 256, As, Bs, acc, 8);

  const int lane = threadIdx.x & 63, wv = threadIdx.x >> 6;
  const int rbase = (wv & 1) * 64 + (lane >> 4) * 4;
  const int cbase = (wv >> 1) * 64 + (lane & 15);
  h16* Srow = Sh + (long)b * NNODE * NNODE;
#pragma unroll
  for (int i = 0; i < 4; ++i) {
#pragma unroll
    for (int e = 0; e < 4; ++e) {
      const long row = nt * 128 + rbase + i * 16 + e;
#pragma unroll
      for (int j = 0; j < 4; ++j) {
        const int col = mt * 128 + cbase + j * 16;
        Srow[row * 2048 + col] = (h16)(acc[i][j][e] * 0.0625f);
      }
    }
  }
}

// ---------------- fused mask + softmax + x_lst_new + attn(f16, in-place) ----------
__device__ __forceinline__ float wred_max(float v) {
#pragma unroll
  for (int off = 32; off > 0; off >>= 1) v = fmaxf(v, __shfl_xor(v, off, 64));
  return v;
}
__device__ __forceinline__ float wred_sum(float v) {
#pragma unroll
  for (int off = 32; off > 0; off >>= 1) v += __shfl_xor(v, off, 64);
  return v;
}

__global__ __launch_bounds__(256) void softmax_kernel(
    h16* __restrict__ Sh, const float* __restrict__ dis, const int* __restrict__ adj,
    const float* __restrict__ x_lst, float* __restrict__ out_x)
{
  const int r = blockIdx.x;                 // 0..8191 (b*2048+n)
  const long ro = (long)r * 2048;
  const int tid = threadIdx.x, lane = tid & 63, wv = tid >> 6;
  const int j0 = tid * 8;
  __shared__ float wmax[4], wsum[4];

  h8v sv = *(const h8v*)(Sh + ro + j0);
  f4v d0 = *(const f4v*)(dis + ro + j0);
  f4v d1 = *(const f4v*)(dis + ro + j0 + 4);
  i4v a0 = *(const i4v*)(adj + ro + j0);
  i4v a1 = *(const i4v*)(adj + ro + j0 + 4);

  float s[8];
#pragma unroll
  for (int k = 0; k < 4; ++k) s[k]     = (a0[k] > 0) ? ((float)sv[k]     - d0[k]) : -1e9f;
#pragma unroll
  for (int k = 0; k < 4; ++k) s[k + 4] = (a1[k] > 0) ? ((float)sv[k + 4] - d1[k]) : -1e9f;

  float m = s[0];
#pragma unroll
  for (int k = 1; k < 8; ++k) m = fmaxf(m, s[k]);
  m = wred_max(m);
  if (lane == 0) wmax[wv] = m;
  __syncthreads();
  m = fmaxf(fmaxf(wmax[0], wmax[1]), fmaxf(wmax[2], wmax[3]));

  float p[8], ls = 0.f;
#pragma unroll
  for (int k = 0; k < 8; ++k) { p[k] = __expf(s[k] - m); ls += p[k]; }
  ls = wred_sum(ls);
  if (lane == 0) wsum[wv] = ls;
  __syncthreads();
  const float inv = 1.0f / (wsum[0] + wsum[1] + wsum[2] + wsum[3]);

  // all reads of Sh happened before the first barrier -> in-place write is safe
  f4v x0 = *(const f4v*)(x_lst + ro + j0);
  f4v x1 = *(const f4v*)(x_lst + ro + j0 + 4);
  f4v o0, o1;
  h8v pv;
#pragma unroll
  for (int k = 0; k < 4; ++k) {
    const float a = p[k] * inv, bq = p[k + 4] * inv;
    o0[k] = x0[k] + a; o1[k] = x1[k] + bq;
    pv[k] = (h16)a; pv[k + 4] = (h16)bq;
  }
  *(f4v*)(out_x + ro + j0) = o0;
  *(f4v*)(out_x + ro + j0 + 4) = o1;
  *(h8v*)(Sh + ro + j0) = pv;
}

// ---------------- AV GEMM (split-K x2): X1p[ks][m][d] f32 partials ----------------
__global__ __launch_bounds__(256) void av_gemm_kernel(
    const h16* __restrict__ Attn, const h16* __restrict__ Vt, float* __restrict__ X1p)
{
  __shared__ __align__(16) h16 As[4096];
  __shared__ __align__(16) h16 Bs[4096];
  const int nt = blockIdx.x, b = blockIdx.z;
  const int ct = blockIdx.y & 1, ks = blockIdx.y >> 1;   // y in [0,4): col-tile x k-split
  const h16* Abase = Attn + ((long)b * NNODE + nt * 128) * 2048 + ks * 1024;
  const h16* Bbase = Vt + ((long)b * 256 + ct * 128) * 2048 + ks * 1024;
  f4v acc[4][4];
  zero_acc(acc);
  gemm_tile(Abase, 2048, Bbase, 2048, As, Bs, acc, 32);

  const int lane = threadIdx.x & 63, wv = threadIdx.x >> 6;
  const int rbase = (wv & 1) * 64 + (lane >> 4) * 4;
  const int cbase = (wv >> 1) * 64 + (lane & 15);
  float* dst = X1p + (long)ks * PARTN;
#pragma unroll
  for (int i = 0; i < 4; ++i) {
#pragma unroll
    for (int e = 0; e < 4; ++e) {
      const long row = (long)b * NNODE + nt * 128 + rbase + i * 16 + e;
#pragma unroll
      for (int j = 0; j < 4; ++j) {
        const int col = ct * 128 + cbase + j * 16;
        dst[row * 256 + col] = acc[i][j][e];
      }
    }
  }
}

// ---------------- MLP GEMM: out = act(A.W^T + bias) -------------------------------
__global__ __launch_bounds__(256) void mlp_gemm_kernel(
    const h16* __restrict__ A, const h16* __restrict__ W, const float* __restrict__ bias,
    h16* __restrict__ outH, float* __restrict__ outF)
{
  __shared__ __align__(16) h16 As[4096];
  __shared__ __align__(16) h16 Bs[4096];
  const int mt = blockIdx.x, ct = blockIdx.y;
  const h16* Abase = A + (long)mt * 128 * 256;
  const h16* Bbase = W + (long)ct * 128 * 256;
  f4v acc[4][4];
  zero_acc(acc);
  gemm_tile(Abase, 256, Bbase, 256, As, Bs, acc, 8);

  const int lane = threadIdx.x & 63, wv = threadIdx.x >> 6;
  const int rbase = (wv & 1) * 64 + (lane >> 4) * 4;
  const int cbase = (wv >> 1) * 64 + (lane & 15);
#pragma unroll
  for (int j = 0; j < 4; ++j) {
    const int gc = ct * 128 + cbase + j * 16;
    const float bias_v = bias[gc];
#pragma unroll
    for (int i = 0; i < 4; ++i) {
#pragma unroll
      for (int e = 0; e < 4; ++e) {
        const long gr = (long)mt * 128 + rbase + i * 16 + e;
        float v = acc[i][j][e] + bias_v;
        if (outH) {
          v = (v >= 0.f) ? v : 0.01f * v;   // leaky_relu
          outH[gr * 256 + gc] = (h16)v;
        } else {
          outF[gr * 256 + gc] = v;
        }
      }
    }
  }
}

// ---------------- fused residual(+partial-sum) + LayerNorm ------------------------
__global__ __launch_bounds__(256) void ln_kernel(
    const float* __restrict__ X, const float* __restrict__ Y, const float* __restrict__ Y2,
    const float* __restrict__ g, const float* __restrict__ bb,
    float* __restrict__ outF, h16* __restrict__ outH)
{
  const int wv = threadIdx.x >> 6, lane = threadIdx.x & 63;
  const long r = (long)blockIdx.x * 4 + wv;
  const long off = r * 256 + lane * 4;
  f4v x = *(const f4v*)(X + off);
  f4v y = *(const f4v*)(Y + off);
  if (Y2) {
    f4v y2 = *(const f4v*)(Y2 + off);
#pragma unroll
    for (int k = 0; k < 4; ++k) y[k] += y2[k];
  }
  float v[4];
  float sum = 0.f, sq = 0.f;
#pragma unroll
  for (int k = 0; k < 4; ++k) { v[k] = x[k] + y[k]; sum += v[k]; sq += v[k] * v[k]; }
  sum = wred_sum(sum);
  sq  = wred_sum(sq);
  const float mu = sum * (1.0f / 256.0f);
  const float var = sq * (1.0f / 256.0f) - mu * mu;
  const float rs = rsqrtf(var + 1e-5f);
  f4v gg = *(const f4v*)(g + lane * 4);
  f4v be = *(const f4v*)(bb + lane * 4);
  f4v o;
#pragma unroll
  for (int k = 0; k < 4; ++k) o[k] = (v[k] - mu) * rs * gg[k] + be[k];
  if (outF) *(f4v*)(outF + off) = o;
  if (outH) {
    _Float16 hv[4];
#pragma unroll
    for (int k = 0; k < 4; ++k) hv[k] = (h16)o[k];
    *(ulong1*)(outH + off) = *(ulong1*)hv;
  }
}

// ---------------- launch ----------------------------------------------------------
extern "C" void kernel_launch(void* const* d_in, const int* in_sizes, int n_in,
                              void* d_out, int out_size, void* d_ws, size_t ws_size,
                              hipStream_t stream)
{
  const float* src  = (const float*)d_in[0];
  const float* xlst = (const float*)d_in[1];
  const int*   adj  = (const int*)d_in[2];
  const float* dis  = (const float*)d_in[3];
  const float* Wq   = (const float*)d_in[4];
  const float* bq   = (const float*)d_in[5];
  const float* Wk   = (const float*)d_in[6];
  const float* bk   = (const float*)d_in[7];
  const float* Wv   = (const float*)d_in[8];
  const float* bvp  = (const float*)d_in[9];
  const float* W1   = (const float*)d_in[10];
  const float* b1   = (const float*)d_in[11];
  const float* W2   = (const float*)d_in[12];
  const float* b2   = (const float*)d_in[13];
  const float* W3   = (const float*)d_in[14];
  const float* b3   = (const float*)d_in[15];
  const float* g1   = (const float*)d_in[16];
  const float* be1  = (const float*)d_in[17];
  const float* g2   = (const float*)d_in[18];
  const float* be2  = (const float*)d_in[19];
  (void)in_sizes; (void)n_in; (void)out_size; (void)ws_size;

  char* ws = (char*)d_ws;
  size_t off = 0;
  auto alloc = [&](size_t bytes) -> void* {
    void* p = ws + off;
    off += (bytes + 1023) & ~(size_t)1023;
    return p;
  };
  // persistent
  h16*   Xpad = (h16*)  alloc((size_t)NBATCH * NPAD * DM * 2);       // 4.2 MB
  h16*   Wt   = (h16*)  alloc((size_t)3 * 256 * 4096 * 2);           // 6.3 MB
  h16*   Wl   = (h16*)  alloc((size_t)3 * 256 * 256 * 2);            // 0.4 MB
  h16*   Qb   = (h16*)  alloc((size_t)QKELEM * 2);                   // 4 MB
  h16*   Kb   = (h16*)  alloc((size_t)QKELEM * 2);                   // 4 MB
  h16*   Vt   = (h16*)  alloc((size_t)QKELEM * 2);                   // 4 MB
  // union region R: conv partials (50 MB, dead after reduce) overlap with the
  // attention/MLP temporaries (71 MB) used afterwards.
  char*  R    = (char*) alloc((size_t)71400 * 1024);                 // ~71.3 MB
  h16*   Qp   = (h16*)R;                                   // [4][m][c]   16.8 MB
  h16*   Kp   = (h16*)(R + (size_t)4 * QKELEM * 2);        // [4][m][c]   16.8 MB
  h16*   Vp   = (h16*)(R + (size_t)8 * QKELEM * 2);        // [4][b][d][m]16.8 MB
  h16*   Sh   = (h16*)R;                                   // 32 MB (over dead Qp/Kp)
  float* X1p  = (float*)(R + (size_t)16 * QKELEM);         // 16.8 MB (over dead Vp)
  float* H    = (float*)(R + (size_t)16 * QKELEM + (size_t)2 * PARTN * 4);
  h16*   H16  = (h16*)((char*)H + (size_t)PARTN * 4);
  h16*   M1   = (h16*)((char*)H16 + (size_t)PARTN * 2);
  h16*   M2   = (h16*)((char*)M1 + (size_t)PARTN * 2);
  float* M3   = X1p;   // partials consumed by ln1 before MLP layer 3 writes

  float* out_h = (float*)d_out;                        // [B,N,d]
  float* out_x = out_h + (size_t)NBATCH * NNODE * DM;  // [B,N,N]

  prep_src_kernel<<<(NBATCH * NPAD * DM) / 256, 256, 0, stream>>>(src, Xpad);
  prep_wconv_kernel<<<3 * 256, 256, 0, stream>>>(Wq, Wk, Wv, Wt);
  prep_wlin_kernel<<<(3 * 256 * 256) / 256, 256, 0, stream>>>(W1, W2, W3, Wl);

  conv_gemm_kernel<<<dim3(64, 2, 12), 256, 0, stream>>>(Xpad, Wt, Qp, Kp, Vp);
  conv_reduce_kernel<<<3 * (QKELEM / 8) / 256, 256, 0, stream>>>(
      Qp, Kp, Vp, bq, bk, bvp, Qb, Kb, Vt);
  scores_gemm_kernel<<<dim3(16, 16, 4), 256, 0, stream>>>(Qb, Kb, Sh);
  softmax_kernel<<<NBATCH * NNODE, 256, 0, stream>>>(Sh, dis, adj, xlst, out_x);
  av_gemm_kernel<<<dim3(16, 4, 4), 256, 0, stream>>>(Sh, Vt, X1p);
  ln_kernel<<<(NBATCH * NNODE) / 4, 256, 0, stream>>>(src, X1p, X1p + PARTN, g1, be1, H, H16);
  mlp_gemm_kernel<<<dim3(64, 2), 256, 0, stream>>>(H16, Wl, b1, M1, nullptr);
  mlp_gemm_kernel<<<dim3(64, 2), 256, 0, stream>>>(M1, Wl + 65536, b2, M2, nullptr);
  mlp_gemm_kernel<<<dim3(64, 2), 256, 0, stream>>>(M2, Wl + 2 * 65536, b3, nullptr, M3);
  ln_kernel<<<(NBATCH * NNODE) / 4, 256, 0, stream>>>(H, M3, nullptr, g2, be2, out_h, nullptr);
}

// Round 5
// 445.007 us; speedup vs baseline: 1.0834x; 1.0399x over previous
//
#include <hip/hip_runtime.h>
#include <stdint.h>

typedef _Float16 h16;
typedef _Float16 h4v __attribute__((ext_vector_type(4)));
typedef _Float16 h8v __attribute__((ext_vector_type(8)));
typedef float    f4v __attribute__((ext_vector_type(4)));
typedef int      i4v __attribute__((ext_vector_type(4)));

#define NBATCH 4
#define NNODE  2048
#define DM     256
#define NPAD   2063       // NNODE + 15 (SAME pad: 7 low, 8 high)
#define QKELEM 2097152    // 8192*256 elements
#define PARTN  (8192 * 256)

// ---------------- async global->LDS (16B per lane, wave-uniform base + lane*16) ----
__device__ __forceinline__ void async16(const void* g, void* l) {
#if __has_builtin(__builtin_amdgcn_global_load_lds)
  __builtin_amdgcn_global_load_lds((__attribute__((address_space(1))) void*)g,
                                   (__attribute__((address_space(3))) void*)l, 16, 0, 0);
#else
  *(f4v*)l = *(const f4v*)g;
#endif
}

// ---------------- shared 128x128xBK32 MFMA GEMM core (round-2 proven version) -----
// Single-buffer, 2-barrier K-loop. Conv plateaus at ~543 TF in this structure;
// explicit dbuf regressed (R3), split-K occupancy didn't move MfmaUtil (R4).
// Per guide m131-141: only a full K-loop restructure goes past this. Frozen.
// XOR swizzle kills the 8-way LDS read conflict (verified: 6.29M -> 0).
__device__ __forceinline__ void gemm_tile(
    const h16* Abase, int astride,
    const h16* Bbase, int bstride,
    h16* As, h16* Bs, f4v acc[4][4], int kiters)
{
  const int tid  = threadIdx.x;
  const int lane = tid & 63;
  const int wv   = tid >> 6;
  const int srow = tid >> 2;
  const int sch  = ((tid & 3) ^ ((tid >> 3) & 3)) * 8;   // swizzled source chunk
  const h16* gA0 = Abase + (long)srow * astride + sch;
  const h16* gA1 = Abase + (long)(srow + 64) * astride + sch;
  const h16* gB0 = Bbase + (long)srow * bstride + sch;
  const h16* gB1 = Bbase + (long)(srow + 64) * bstride + sch;
  h16* lA0 = As + tid * 8;
  h16* lA1 = As + 2048 + tid * 8;
  h16* lB0 = Bs + tid * 8;
  h16* lB1 = Bs + 2048 + tid * 8;
  const int swz = ((lane & 15) >> 1) & 3;
  const int qq  = ((lane >> 4) ^ swz) * 8;
  const int amr = ((wv & 1) * 64 + (lane & 15)) * 32 + qq;
  const int bnr = ((wv >> 1) * 64 + (lane & 15)) * 32 + qq;

  for (int kt = 0; kt < kiters; ++kt) {
    const int k0 = kt * 32;
    __syncthreads();
    async16(gA0 + k0, lA0);
    async16(gA1 + k0, lA1);
    async16(gB0 + k0, lB0);
    async16(gB1 + k0, lB1);
    asm volatile("s_waitcnt vmcnt(0)" ::: "memory");
    __syncthreads();
    h8v af[4], bf[4];
#pragma unroll
    for (int i = 0; i < 4; ++i) af[i] = *(const h8v*)(As + amr + i * 512);
#pragma unroll
    for (int j = 0; j < 4; ++j) bf[j] = *(const h8v*)(Bs + bnr + j * 512);
#pragma unroll
    for (int i = 0; i < 4; ++i)
#pragma unroll
      for (int j = 0; j < 4; ++j)
        acc[i][j] = __builtin_amdgcn_mfma_f32_16x16x32_f16(af[i], bf[j], acc[i][j], 0, 0, 0);
  }
}

__device__ __forceinline__ void zero_acc(f4v acc[4][4]) {
#pragma unroll
  for (int i = 0; i < 4; ++i)
#pragma unroll
    for (int j = 0; j < 4; ++j) {
      f4v z = {0.f, 0.f, 0.f, 0.f};
      acc[i][j] = z;
    }
}

// ---------------- merged prep kernel (src pad + conv-W transpose + lin-W cast) ----
#define NSRC_BLK 8252   // NBATCH*NPAD*DM/256
__global__ __launch_bounds__(256) void prep_all_kernel(
    const float* __restrict__ src,
    const float* __restrict__ Wq, const float* __restrict__ Wk, const float* __restrict__ Wv,
    const float* __restrict__ W1, const float* __restrict__ W2, const float* __restrict__ W3,
    h16* __restrict__ Xpad, h16* __restrict__ Wt, h16* __restrict__ Wl)
{
  __shared__ float plds[16][257];
  const int bi = blockIdx.x, tid = threadIdx.x;
  if (bi < NSRC_BLK) {
    int idx = bi * 256 + tid;
    int c = idx & 255;
    int row = idx >> 8;
    int b = row / NPAD;
    int n = row - b * NPAD;
    float v = 0.f;
    int ns = n - 7;
    if (ns >= 0 && ns < NNODE) v = src[((long)b * NNODE + ns) * DM + c];
    Xpad[idx] = (h16)v;
  } else if (bi < NSRC_BLK + 768) {
    // coalesced read of W[o][c][t], LDS transpose, coalesced write Wt[w][o][t][c]
    const int q = bi - NSRC_BLK;
    const int w = q >> 8, o = q & 255;
    const float* W = (w == 0) ? Wq : (w == 1) ? Wk : Wv;
    const float* base = W + (long)o * 4096;
    f4v r0 = *(const f4v*)(base + tid * 16);
    f4v r1 = *(const f4v*)(base + tid * 16 + 4);
    f4v r2 = *(const f4v*)(base + tid * 16 + 8);
    f4v r3 = *(const f4v*)(base + tid * 16 + 12);
#pragma unroll
    for (int k = 0; k < 4; ++k) {
      plds[k][tid] = r0[k]; plds[4 + k][tid] = r1[k];
      plds[8 + k][tid] = r2[k]; plds[12 + k][tid] = r3[k];
    }
    __syncthreads();
    const int t = tid >> 4, c0 = (tid & 15) * 16;
    h16* out = Wt + ((long)(w * 256 + o)) * 4096 + t * 256 + c0;
    h8v o0, o1;
#pragma unroll
    for (int k = 0; k < 8; ++k) { o0[k] = (h16)plds[t][c0 + k]; o1[k] = (h16)plds[t][c0 + 8 + k]; }
    *(h8v*)out = o0;
    *(h8v*)(out + 8) = o1;
  } else {
    int idx = (bi - NSRC_BLK - 768) * 256 + tid;   // over 3*65536
    int w = idx >> 16;
    int rem = idx & 65535;
    const float* W = (w == 0) ? W1 : (w == 1) ? W2 : W3;
    Wl[idx] = (h16)W[rem];
  }
}

// ---------------- conv GEMM, split-K x4: f16 partials ------------------------------
__global__ __launch_bounds__(256) void conv_gemm_kernel(
    const h16* __restrict__ Xpad, const h16* __restrict__ Wt,
    h16* __restrict__ Qp, h16* __restrict__ Kp, h16* __restrict__ Vp)
{
  __shared__ __align__(16) h16 As[4096];
  __shared__ __align__(16) h16 Bs[4096];
  const int mt = blockIdx.x, ct = blockIdx.y;
  const int w = blockIdx.z >> 2, ks = blockIdx.z & 3;
  const int m0 = mt * 128;
  const int b = m0 >> 11, n0 = m0 & 2047;
  const h16* Abase = Xpad + ((long)(b * NPAD + n0)) * DM + ks * 1024;
  const h16* Bbase = Wt + (long)w * (256 * 4096) + (long)ct * 128 * 4096 + ks * 1024;
  f4v acc[4][4];
  zero_acc(acc);
  gemm_tile(Abase, DM, Bbase, 4096, As, Bs, acc, 32);

  h16* dst = ((w == 0) ? Qp : (w == 1) ? Kp : Vp) + (long)ks * QKELEM;
  const int lane = threadIdx.x & 63, wv = threadIdx.x >> 6;
  const int rbase = (wv & 1) * 64 + (lane >> 4) * 4;
  const int cbase = (wv >> 1) * 64 + (lane & 15);
#pragma unroll
  for (int j = 0; j < 4; ++j) {
    const int gc = ct * 128 + cbase + j * 16;
#pragma unroll
    for (int i = 0; i < 4; ++i) {
#pragma unroll
      for (int e = 0; e < 4; ++e) {
        const int gr = m0 + rbase + i * 16 + e;
        const h16 v = (h16)acc[i][j][e];
        if (w == 2) {
          const int bb = gr >> 11, n = gr & 2047;
          dst[((long)(bb * 256 + gc)) * 2048 + n] = v;
        } else {
          dst[(long)gr * 256 + gc] = v;
        }
      }
    }
  }
}

// ---------------- conv reduce: sum 4 partials + bias -> Q,K [m][c], Vt [b][d][m] --
__global__ __launch_bounds__(256) void conv_reduce_kernel(
    const h16* __restrict__ Qp, const h16* __restrict__ Kp, const h16* __restrict__ Vp,
    const float* __restrict__ bq, const float* __restrict__ bk, const float* __restrict__ bv,
    h16* __restrict__ Qb, h16* __restrict__ Kb, h16* __restrict__ Vt)
{
  const long gid = (long)blockIdx.x * 256 + threadIdx.x;
  if (gid < 2 * (QKELEM / 8)) {
    const int which = gid >= (QKELEM / 8);
    const long e = (gid - (long)which * (QKELEM / 8)) * 8;
    const h16* P = which ? Kp : Qp;
    const float* bias = which ? bk : bq;
    float s[8] = {0.f, 0.f, 0.f, 0.f, 0.f, 0.f, 0.f, 0.f};
#pragma unroll
    for (int ks = 0; ks < 4; ++ks) {
      h8v p = *(const h8v*)(P + (long)ks * QKELEM + e);
#pragma unroll
      for (int k = 0; k < 8; ++k) s[k] += (float)p[k];
    }
    const int c0 = (int)(e & 255);
    h8v o;
#pragma unroll
    for (int k = 0; k < 8; ++k) o[k] = (h16)(s[k] + bias[c0 + k]);
    *(h8v*)((which ? Kb : Qb) + e) = o;
  } else {
    const long e = (gid - 2 * (QKELEM / 8)) * 8;     // over [b][d][m]
    float s[8] = {0.f, 0.f, 0.f, 0.f, 0.f, 0.f, 0.f, 0.f};
#pragma unroll
    for (int ks = 0; ks < 4; ++ks) {
      h8v p = *(const h8v*)(Vp + (long)ks * QKELEM + e);
#pragma unroll
      for (int k = 0; k < 8; ++k) s[k] += (float)p[k];
    }
    const float bias_v = bv[(int)((e >> 11) & 255)];
    h8v o;
#pragma unroll
    for (int k = 0; k < 8; ++k) o[k] = (h16)(s[k] + bias_v);
    *(h8v*)(Vt + e) = o;
  }
}

// ---------------- scores GEMM: S[b][n][m] f16 = (Q.K^T)*scale ---------------------
__global__ __launch_bounds__(256) void scores_gemm_kernel(
    const h16* __restrict__ Q, const h16* __restrict__ Km, h16* __restrict__ Sh)
{
  __shared__ __align__(16) h16 As[4096];
  __shared__ __align__(16) h16 Bs[4096];
  const int nt = blockIdx.x, mt = blockIdx.y, b = blockIdx.z;
  const h16* Abase = Q + ((long)b * NNODE + nt * 128) * 256;
  const h16* Bbase = Km + ((long)b * NNODE + mt * 128) * 256;
  f4v acc[4][4];
  zero_acc(acc);
  gemm_tile(Abase, 256, Bbase, 256, As, Bs, acc, 8);

  const int lane = threadIdx.x & 63, wv = threadIdx.x >> 6;
  const int rbase = (wv & 1) * 64 + (lane >> 4) * 4;
  const int cbase = (wv >> 1) * 64 + (lane & 15);
  h16* Srow = Sh + (long)b * NNODE * NNODE;
#pragma unroll
  for (int i = 0; i < 4; ++i) {
#pragma unroll
    for (int e = 0; e < 4; ++e) {
      const long row = nt * 128 + rbase + i * 16 + e;
#pragma unroll
      for (int j = 0; j < 4; ++j) {
        const int col = mt * 128 + cbase + j * 16;
        Srow[row * 2048 + col] = (h16)(acc[i][j][e] * 0.0625f);
      }
    }
  }
}

// ---------------- fused mask + softmax + x_lst_new + attn(f16, in-place) ----------
__device__ __forceinline__ float wred_max(float v) {
#pragma unroll
  for (int off = 32; off > 0; off >>= 1) v = fmaxf(v, __shfl_xor(v, off, 64));
  return v;
}
__device__ __forceinline__ float wred_sum(float v) {
#pragma unroll
  for (int off = 32; off > 0; off >>= 1) v += __shfl_xor(v, off, 64);
  return v;
}

__global__ __launch_bounds__(256) void softmax_kernel(
    h16* __restrict__ Sh, const float* __restrict__ dis, const int* __restrict__ adj,
    const float* __restrict__ x_lst, float* __restrict__ out_x)
{
  const int r = blockIdx.x;                 // 0..8191 (b*2048+n)
  const long ro = (long)r * 2048;
  const int tid = threadIdx.x, lane = tid & 63, wv = tid >> 6;
  const int j0 = tid * 8;
  __shared__ float wmax[4], wsum[4];

  h8v sv = *(const h8v*)(Sh + ro + j0);
  f4v d0 = *(const f4v*)(dis + ro + j0);
  f4v d1 = *(const f4v*)(dis + ro + j0 + 4);
  i4v a0 = *(const i4v*)(adj + ro + j0);
  i4v a1 = *(const i4v*)(adj + ro + j0 + 4);

  float s[8];
#pragma unroll
  for (int k = 0; k < 4; ++k) s[k]     = (a0[k] > 0) ? ((float)sv[k]     - d0[k]) : -1e9f;
#pragma unroll
  for (int k = 0; k < 4; ++k) s[k + 4] = (a1[k] > 0) ? ((float)sv[k + 4] - d1[k]) : -1e9f;

  float m = s[0];
#pragma unroll
  for (int k = 1; k < 8; ++k) m = fmaxf(m, s[k]);
  m = wred_max(m);
  if (lane == 0) wmax[wv] = m;
  __syncthreads();
  m = fmaxf(fmaxf(wmax[0], wmax[1]), fmaxf(wmax[2], wmax[3]));

  float p[8], ls = 0.f;
#pragma unroll
  for (int k = 0; k < 8; ++k) { p[k] = __expf(s[k] - m); ls += p[k]; }
  ls = wred_sum(ls);
  if (lane == 0) wsum[wv] = ls;
  __syncthreads();
  const float inv = 1.0f / (wsum[0] + wsum[1] + wsum[2] + wsum[3]);

  f4v x0 = *(const f4v*)(x_lst + ro + j0);
  f4v x1 = *(const f4v*)(x_lst + ro + j0 + 4);
  f4v o0, o1;
  h8v pv;
#pragma unroll
  for (int k = 0; k < 4; ++k) {
    const float a = p[k] * inv, bq = p[k + 4] * inv;
    o0[k] = x0[k] + a; o1[k] = x1[k] + bq;
    pv[k] = (h16)a; pv[k + 4] = (h16)bq;
  }
  *(f4v*)(out_x + ro + j0) = o0;
  *(f4v*)(out_x + ro + j0 + 4) = o1;
  *(h8v*)(Sh + ro + j0) = pv;
}

// ---------------- AV GEMM (split-K x2): X1p[ks][m][d] f16 partials ----------------
__global__ __launch_bounds__(256) void av_gemm_kernel(
    const h16* __restrict__ Attn, const h16* __restrict__ Vt, h16* __restrict__ X1p)
{
  __shared__ __align__(16) h16 As[4096];
  __shared__ __align__(16) h16 Bs[4096];
  const int nt = blockIdx.x, b = blockIdx.z;
  const int ct = blockIdx.y & 1, ks = blockIdx.y >> 1;
  const h16* Abase = Attn + ((long)b * NNODE + nt * 128) * 2048 + ks * 1024;
  const h16* Bbase = Vt + ((long)b * 256 + ct * 128) * 2048 + ks * 1024;
  f4v acc[4][4];
  zero_acc(acc);
  gemm_tile(Abase, 2048, Bbase, 2048, As, Bs, acc, 32);

  const int lane = threadIdx.x & 63, wv = threadIdx.x >> 6;
  const int rbase = (wv & 1) * 64 + (lane >> 4) * 4;
  const int cbase = (wv >> 1) * 64 + (lane & 15);
  h16* dst = X1p + (long)ks * PARTN;
#pragma unroll
  for (int i = 0; i < 4; ++i) {
#pragma unroll
    for (int e = 0; e < 4; ++e) {
      const long row = (long)b * NNODE + nt * 128 + rbase + i * 16 + e;
#pragma unroll
      for (int j = 0; j < 4; ++j) {
        const int col = ct * 128 + cbase + j * 16;
        dst[row * 256 + col] = (h16)acc[i][j][e];
      }
    }
  }
}

// ---------------- fused residual + partial-sum + LayerNorm1 -----------------------
__global__ __launch_bounds__(256) void ln1_kernel(
    const float* __restrict__ X, const h16* __restrict__ Y, const h16* __restrict__ Y2,
    const float* __restrict__ g, const float* __restrict__ bb,
    float* __restrict__ outF, h16* __restrict__ outH)
{
  const int wv = threadIdx.x >> 6, lane = threadIdx.x & 63;
  const long r = (long)blockIdx.x * 4 + wv;
  const long off = r * 256 + lane * 4;
  f4v x = *(const f4v*)(X + off);
  h4v y = *(const h4v*)(Y + off);
  h4v y2 = *(const h4v*)(Y2 + off);
  float v[4];
  float sum = 0.f, sq = 0.f;
#pragma unroll
  for (int k = 0; k < 4; ++k) {
    v[k] = x[k] + (float)y[k] + (float)y2[k];
    sum += v[k]; sq += v[k] * v[k];
  }
  sum = wred_sum(sum);
  sq  = wred_sum(sq);
  const float mu = sum * (1.0f / 256.0f);
  const float var = sq * (1.0f / 256.0f) - mu * mu;
  const float rs = rsqrtf(var + 1e-5f);
  f4v gg = *(const f4v*)(g + lane * 4);
  f4v be = *(const f4v*)(bb + lane * 4);
  f4v o;
#pragma unroll
  for (int k = 0; k < 4; ++k) o[k] = (v[k] - mu) * rs * gg[k] + be[k];
  *(f4v*)(outF + off) = o;
  h4v hv;
#pragma unroll
  for (int k = 0; k < 4; ++k) hv[k] = (h16)o[k];
  *(h4v*)(outH + off) = hv;
}

// ---------------- fused 3-layer MLP + residual + LayerNorm2 -----------------------
// 256 blocks x 32 rows. Intermediates live in LDS ([32][264] h16, padded row ->
// 2-way bank aliasing only). Weights streamed per 32-k tile via global_load_lds
// with the XOR swizzle (same layout as gemm_tile's Bs). LN2 fused in tail.
__global__ __launch_bounds__(256) void mlp_fused_kernel(
    const h16* __restrict__ H16, const float* __restrict__ Hf,
    const h16* __restrict__ Wl,
    const float* __restrict__ b1, const float* __restrict__ b2, const float* __restrict__ b3,
    const float* __restrict__ g2, const float* __restrict__ be2,
    float* __restrict__ out_h)
{
  __shared__ h16 Xa[32][264];
  __shared__ h16 Xb[32][264];
  __shared__ __align__(16) h16 Bs[8192];      // 256 out-cols x 32 k
  const int tid = threadIdx.x, lane = tid & 63, wv = tid >> 6;
  const int m0 = blockIdx.x * 32;

  { // load LN1 output rows into Xa (coalesced global, padded LDS writes)
    const int r = tid >> 3, cq = (tid & 7) * 32;
    const h16* s = H16 + (long)(m0 + r) * 256 + cq;
#pragma unroll
    for (int k = 0; k < 4; ++k)
      *(h8v*)&Xa[r][cq + k * 8] = *(const h8v*)(s + k * 8);
  }

  const int srow = tid >> 2;
  const int sch  = ((tid & 3) ^ ((tid >> 3) & 3)) * 8;
  h16* lB = Bs + tid * 8;
  const int quad = lane >> 4;
  const float* biases[3] = {b1, b2, b3};

  for (int layer = 0; layer < 3; ++layer) {
    const h16* W = Wl + layer * 65536;
    const h16 (*Xi)[264] = (layer == 1) ? (const h16(*)[264])Xb : (const h16(*)[264])Xa;
    h16 (*Xo)[264] = (layer == 1) ? Xa : Xb;
    f4v acc[2][4];
#pragma unroll
    for (int i = 0; i < 2; ++i)
#pragma unroll
      for (int j = 0; j < 4; ++j) { f4v z = {0.f,0.f,0.f,0.f}; acc[i][j] = z; }

    for (int kt = 0; kt < 8; ++kt) {
      __syncthreads();
      const h16* gB = W + (long)srow * 256 + kt * 32 + sch;
      async16(gB, lB);
      async16(gB + 64 * 256, lB + 64 * 32);
      async16(gB + 128 * 256, lB + 128 * 32);
      async16(gB + 192 * 256, lB + 192 * 32);
      asm volatile("s_waitcnt vmcnt(0)" ::: "memory");
      __syncthreads();
      h8v af[2], bf[4];
#pragma unroll
      for (int i = 0; i < 2; ++i)
        af[i] = *(const h8v*)&Xi[i * 16 + (lane & 15)][kt * 32 + quad * 8];
#pragma unroll
      for (int j = 0; j < 4; ++j) {
        const int n = wv * 64 + j * 16 + (lane & 15);
        const int q = (quad ^ ((n >> 1) & 3)) * 8;
        bf[j] = *(const h8v*)(Bs + n * 32 + q);
      }
#pragma unroll
      for (int i = 0; i < 2; ++i)
#pragma unroll
        for (int j = 0; j < 4; ++j)
          acc[i][j] = __builtin_amdgcn_mfma_f32_16x16x32_f16(af[i], bf[j], acc[i][j], 0, 0, 0);
    }
    // epilogue: bias (+leaky for layers 0/1), write to Xo (other buffer -> no race)
    const int rb = quad * 4;
    const int cb = wv * 64 + (lane & 15);
    const float* bias = biases[layer];
    const bool leaky = (layer < 2);
#pragma unroll
    for (int j = 0; j < 4; ++j) {
      const int col = cb + j * 16;
      const float bv = bias[col];
#pragma unroll
      for (int i = 0; i < 2; ++i)
#pragma unroll
        for (int e = 0; e < 4; ++e) {
          float v = acc[i][j][e] + bv;
          if (leaky) v = (v >= 0.f) ? v : 0.01f * v;
          Xo[i * 16 + rb + e][col] = (h16)v;
        }
    }
  }
  __syncthreads();

  // LN2: rows in Xb (layer-3 out), residual Hf, write out_h. 8 threads/row.
  const int r = tid >> 3, c0 = (tid & 7) * 32;
  const float* hrow = Hf + (long)(m0 + r) * 256 + c0;
  float v[32];
  float s = 0.f, sq = 0.f;
#pragma unroll
  for (int k8 = 0; k8 < 8; ++k8) {
    f4v h4 = *(const f4v*)(hrow + k8 * 4);
#pragma unroll
    for (int e = 0; e < 4; ++e) {
      float t = (float)Xb[r][c0 + k8 * 4 + e] + h4[e];
      v[k8 * 4 + e] = t; s += t; sq += t * t;
    }
  }
#pragma unroll
  for (int off = 1; off < 8; off <<= 1) { s += __shfl_xor(s, off, 64); sq += __shfl_xor(sq, off, 64); }
  const float mu = s * (1.0f / 256.0f);
  const float var = sq * (1.0f / 256.0f) - mu * mu;
  const float rs = rsqrtf(var + 1e-5f);
  float* orow = out_h + (long)(m0 + r) * 256 + c0;
#pragma unroll
  for (int k8 = 0; k8 < 8; ++k8) {
    f4v gg = *(const f4v*)(g2 + c0 + k8 * 4);
    f4v be = *(const f4v*)(be2 + c0 + k8 * 4);
    f4v o;
#pragma unroll
    for (int e = 0; e < 4; ++e) o[e] = (v[k8 * 4 + e] - mu) * rs * gg[e] + be[e];
    *(f4v*)(orow + k8 * 4) = o;
  }
}

// ---------------- launch ----------------------------------------------------------
extern "C" void kernel_launch(void* const* d_in, const int* in_sizes, int n_in,
                              void* d_out, int out_size, void* d_ws, size_t ws_size,
                              hipStream_t stream)
{
  const float* src  = (const float*)d_in[0];
  const float* xlst = (const float*)d_in[1];
  const int*   adj  = (const int*)d_in[2];
  const float* dis  = (const float*)d_in[3];
  const float* Wq   = (const float*)d_in[4];
  const float* bq   = (const float*)d_in[5];
  const float* Wk   = (const float*)d_in[6];
  const float* bk   = (const float*)d_in[7];
  const float* Wv   = (const float*)d_in[8];
  const float* bvp  = (const float*)d_in[9];
  const float* W1   = (const float*)d_in[10];
  const float* b1   = (const float*)d_in[11];
  const float* W2   = (const float*)d_in[12];
  const float* b2   = (const float*)d_in[13];
  const float* W3   = (const float*)d_in[14];
  const float* b3   = (const float*)d_in[15];
  const float* g1   = (const float*)d_in[16];
  const float* be1  = (const float*)d_in[17];
  const float* g2   = (const float*)d_in[18];
  const float* be2  = (const float*)d_in[19];
  (void)in_sizes; (void)n_in; (void)out_size; (void)ws_size;

  char* ws = (char*)d_ws;
  size_t off = 0;
  auto alloc = [&](size_t bytes) -> void* {
    void* p = ws + off;
    off += (bytes + 1023) & ~(size_t)1023;
    return p;
  };
  h16*   Xpad = (h16*)  alloc((size_t)NBATCH * NPAD * DM * 2);       // 4.2 MB
  h16*   Wt   = (h16*)  alloc((size_t)3 * 256 * 4096 * 2);           // 6.3 MB
  h16*   Wl   = (h16*)  alloc((size_t)3 * 256 * 256 * 2);            // 0.4 MB
  h16*   Qb   = (h16*)  alloc((size_t)QKELEM * 2);                   // 4 MB
  h16*   Kb   = (h16*)  alloc((size_t)QKELEM * 2);                   // 4 MB
  h16*   Vt   = (h16*)  alloc((size_t)QKELEM * 2);                   // 4 MB
  // union region R: conv partials (50.3 MB, dead after reduce) overlap Sh/X1p.
  char*  R    = (char*) alloc((size_t)66000 * 1024);                 // ~64.5 MB
  h16*   Qp   = (h16*)R;                                   // [4][m][c]    16.8 MB
  h16*   Kp   = (h16*)(R + (size_t)4 * QKELEM * 2);        // [4][m][c]    16.8 MB
  h16*   Vp   = (h16*)(R + (size_t)8 * QKELEM * 2);        // [4][b][d][m] 16.8 MB
  h16*   Sh   = (h16*)R;                                   // 32 MB (over dead Qp/Kp)
  h16*   X1p  = Vp;                                        // 8.4 MB (over dead Vp)
  float* H    = (float*)(R + (size_t)12 * QKELEM * 2);     // 8 MB
  h16*   H16  = (h16*)((char*)H + (size_t)PARTN * 4);      // 4 MB

  float* out_h = (float*)d_out;                        // [B,N,d]
  float* out_x = out_h + (size_t)NBATCH * NNODE * DM;  // [B,N,N]

  prep_all_kernel<<<NSRC_BLK + 768 + 768, 256, 0, stream>>>(
      src, Wq, Wk, Wv, W1, W2, W3, Xpad, Wt, Wl);
  conv_gemm_kernel<<<dim3(64, 2, 12), 256, 0, stream>>>(Xpad, Wt, Qp, Kp, Vp);
  conv_reduce_kernel<<<3 * (QKELEM / 8) / 256, 256, 0, stream>>>(
      Qp, Kp, Vp, bq, bk, bvp, Qb, Kb, Vt);
  scores_gemm_kernel<<<dim3(16, 16, 4), 256, 0, stream>>>(Qb, Kb, Sh);
  softmax_kernel<<<NBATCH * NNODE, 256, 0, stream>>>(Sh, dis, adj, xlst, out_x);
  av_gemm_kernel<<<dim3(16, 4, 4), 256, 0, stream>>>(Sh, Vt, X1p);
  ln1_kernel<<<(NBATCH * NNODE) / 4, 256, 0, stream>>>(src, X1p, X1p + PARTN, g1, be1, H, H16);
  mlp_fused_kernel<<<NBATCH * NNODE / 32, 256, 0, stream>>>(
      H16, H, Wl, b1, b2, b3, g2, be2, out_h);
}